// Round 14
// baseline (979.702 us; speedup 1.0000x reference)
//
#include <hip/hip_runtime.h>
#include <hip/hip_bf16.h>
#include <math.h>

#define BB    4
#define NN    100000
#define NFEAT 11
#define NSP   512
#define NSEG  (BB*NSP)     // 2048
#define NPTS  (BB*NN)      // 400000
#define H2    256
#define H3    512
#define EE    384
#define MT    64           // main M-tile rows (NPTS % MT == 0)
#define GS    (MT*8)       // granule stride in ushorts
#define MI_N  (MT/16)
#define MAXL  15           // fallback main: max distinct segments per tile
#define MAXL2 10           // main_v5: max distinct segments per tile
#define RSEG  512          // gmax kernel rows per block
#define MAXS  12           // gmax kernel: max distinct segments per block
#define ENCNI 0x007FFFFFu  // enc(-inf)

typedef __attribute__((ext_vector_type(8))) short short8;
typedef __attribute__((ext_vector_type(4))) float f32x4;

__device__ __forceinline__ ushort f2bf(float f) {
  unsigned u = __builtin_bit_cast(unsigned, f);
  unsigned r = (u + 0x7FFFu + ((u >> 16) & 1u)) >> 16;
  return (ushort)r;
}
__device__ __forceinline__ unsigned encf(float f) {
  unsigned u = __builtin_bit_cast(unsigned, f);
  return u ^ ((unsigned)((int)u >> 31) | 0x80000000u);
}
__device__ __forceinline__ float decf(unsigned e) {
  unsigned u = (e & 0x80000000u) ? (e ^ 0x80000000u) : ~e;
  return __builtin_bit_cast(float, u);
}

// ---------------- init enc buffers + weight prep + histogram ----------------
__global__ void prep_init(const float* __restrict__ W1, const float* __restrict__ b1,
                          const float* __restrict__ W2, const float* __restrict__ b2,
                          const float* __restrict__ W3, const float* __restrict__ W4,
                          const int* __restrict__ sidx,
                          float* __restrict__ W12, float* __restrict__ b12,
                          float* __restrict__ W3gT, ushort* __restrict__ W3hP,
                          ushort* __restrict__ W4P,
                          int* __restrict__ counts,
                          unsigned* __restrict__ gmaxEnc, unsigned* __restrict__ out_enc) {
  int u = blockIdx.x * 256 + threadIdx.x;
  if (u < NSEG * EE) out_enc[u] = ENCNI;
  if (u < NSEG * H2) gmaxEnc[u] = ENCNI;
  if (u < NPTS) {
    int seg = sidx[u] + (u / NN) * NSP;
    atomicAdd(&counts[seg], 1);
  }

  if (u < H2 * NFEAT) {
    int c = u / NFEAT, f = u - c * NFEAT;
    float acc = 0.f;
    for (int j = 0; j < 128; ++j) acc += W2[c * 128 + j] * W1[j * NFEAT + f];
    W12[u] = acc;
  } else if (u < 3072) {
    int c = u - H2 * NFEAT;
    float acc = b2[c];
    for (int j = 0; j < 128; ++j) acc += W2[c * 128 + j] * b1[j];
    b12[c] = acc;
  } else if (u < 3072 + 131072) {
    int v = u - 3072;
    int c = v >> 9, o = v & 511;
    W3gT[v] = W3[o * H3 + c];
  } else if (u < 134144 + 16384) {
    int v = u - 134144;
    int ks = v >> 11, rem = v & 2047;
    int nt = rem >> 6, l = rem & 63;
    int n = nt * 16 + (l & 15);
    #pragma unroll
    for (int j = 0; j < 8; ++j) {
      int k = ks * 32 + (l >> 4) * 8 + j;
      W3hP[(size_t)v * 8 + j] = f2bf(W3[n * H3 + H2 + k]);
    }
  } else if (u < 150528 + 24576) {
    int v = u - 150528;
    int ks = v / 1536, rem = v - ks * 1536;
    int nt = rem >> 6, l = rem & 63;
    int n = nt * 16 + (l & 15);
    #pragma unroll
    for (int j = 0; j < 8; ++j) {
      int k = ks * 32 + (l >> 4) * 8 + j;
      W4P[(size_t)v * 8 + j] = f2bf(W4[n * H3 + k]);
    }
  }
}

__global__ void scan_kernel(const int* __restrict__ counts, int* __restrict__ offs) {
  __shared__ int buf[1024];
  int t = threadIdx.x;
  int c0 = counts[2 * t], c1 = counts[2 * t + 1];
  int s = c0 + c1;
  buf[t] = s;
  __syncthreads();
  for (int d = 1; d < 1024; d <<= 1) {
    int add = (t >= d) ? buf[t - d] : 0;
    __syncthreads();
    buf[t] += add;
    __syncthreads();
  }
  int incl = buf[t];
  int excl = incl - s;
  offs[2 * t] = excl;
  offs[2 * t + 1] = excl + c0;
  if (t == 1023) offs[2048] = incl;
}

__global__ void scatter_kernel(const int* __restrict__ sidx, const int* __restrict__ offs,
                               int* __restrict__ cursor, int* __restrict__ perm,
                               int* __restrict__ segp) {
  int i = blockIdx.x * blockDim.x + threadIdx.x;
  if (i < NPTS) {
    int seg = sidx[i] + (i / NN) * NSP;
    int pos = offs[seg] + atomicAdd(&cursor[seg], 1);
    perm[pos] = i;
    segp[pos] = seg;
  }
}

// ---------------- gmax (+optional h store), validated R8/R9/R11 ----------------
template <bool STOREH>
__global__ __launch_bounds__(512) void gmax_kernel(
    const float* __restrict__ x, const int* __restrict__ perm,
    const int* __restrict__ segp,
    const float* __restrict__ W12, const float* __restrict__ b12,
    unsigned* __restrict__ gmaxEnc, ushort* __restrict__ hG) {
  __shared__ float xs[RSEG * NFEAT];
  __shared__ float W12s[H2 * NFEAT];
  __shared__ float b12s[H2];
  __shared__ int   segd[RSEG];
  __shared__ unsigned gmaxL[MAXS * H2];

  const int t = threadIdx.x;
  const int mbeg = blockIdx.x * RSEG;
  const int nvalid = min(RSEG, NPTS - mbeg);

  for (int u = t; u < RSEG * NFEAT; u += 512) {
    int p = u / NFEAT, f = u - p * NFEAT;
    xs[u] = (p < nvalid) ? x[(size_t)perm[mbeg + p] * NFEAT + f] : 0.f;
  }
  for (int u = t; u < H2 * NFEAT; u += 512) W12s[u] = W12[u];
  if (t < H2) b12s[t] = b12[t];
  segd[t] = (t < nvalid) ? segp[mbeg + t] : segp[mbeg + nvalid - 1];
  for (int u = t; u < MAXS * H2; u += 512) gmaxL[u] = ENCNI;
  __syncthreads();

  const int s_lo = segd[0];
  const int s_hi = segd[nvalid - 1];
  const bool fb = (s_hi - s_lo + 1) > MAXS;

  const int g  = t >> 4;
  const int r0 = t & 15;
  const int cb = g * 8;

  float w12r[8][NFEAT], bbr[8];
  #pragma unroll
  for (int cj = 0; cj < 8; ++cj) {
    bbr[cj] = b12s[cb + cj];
    #pragma unroll
    for (int f = 0; f < NFEAT; ++f) w12r[cj][f] = W12s[(cb + cj) * NFEAT + f];
  }

  float m[8];
  #pragma unroll
  for (int cj = 0; cj < 8; ++cj) m[cj] = -INFINITY;
  int cur = segd[r0];
  bool any = false;

  for (int k = 0; k < 32; ++k) {
    int row = r0 + k * 16;
    if (row >= nvalid) break;
    int sg = segd[row];
    if (sg != cur) {
      #pragma unroll
      for (int cj = 0; cj < 8; ++cj) {
        unsigned e = encf(m[cj]);
        if (fb) atomicMax(&gmaxEnc[(size_t)cur * H2 + cb + cj], e);
        else    atomicMax(&gmaxL[(cur - s_lo) * H2 + cb + cj], e);
      }
      cur = sg;
      #pragma unroll
      for (int cj = 0; cj < 8; ++cj) m[cj] = -INFINITY;
    }
    float acc[8];
    #pragma unroll
    for (int cj = 0; cj < 8; ++cj) acc[cj] = bbr[cj];
    #pragma unroll
    for (int f = 0; f < NFEAT; ++f) {
      float xv = xs[row * NFEAT + f];
      #pragma unroll
      for (int cj = 0; cj < 8; ++cj) acc[cj] += w12r[cj][f] * xv;
    }
    if (STOREH) {
      uint4 pkt;
      pkt.x = (unsigned)f2bf(acc[0]) | ((unsigned)f2bf(acc[1]) << 16);
      pkt.y = (unsigned)f2bf(acc[2]) | ((unsigned)f2bf(acc[3]) << 16);
      pkt.z = (unsigned)f2bf(acc[4]) | ((unsigned)f2bf(acc[5]) << 16);
      pkt.w = (unsigned)f2bf(acc[6]) | ((unsigned)f2bf(acc[7]) << 16);
      int pt = mbeg + row;
      *(uint4*)&hG[(size_t)(pt >> 6) * 16384 + ((size_t)g * 64 + (pt & 63)) * 8] = pkt;
    }
    #pragma unroll
    for (int cj = 0; cj < 8; ++cj) m[cj] = fmaxf(m[cj], acc[cj]);
    any = true;
  }
  if (any) {
    #pragma unroll
    for (int cj = 0; cj < 8; ++cj) {
      unsigned e = encf(m[cj]);
      if (fb) atomicMax(&gmaxEnc[(size_t)cur * H2 + cb + cj], e);
      else    atomicMax(&gmaxL[(cur - s_lo) * H2 + cb + cj], e);
    }
  }

  __syncthreads();
  if (!fb) {
    int nloc = s_hi - s_lo + 1;
    for (int u = t; u < nloc * H2; u += 512) {
      int sg = s_lo + (u >> 8);
      unsigned v = gmaxL[u];
      if (sg > s_lo && sg < s_hi) gmaxEnc[(size_t)sg * H2 + (u & 255)] = v;
      else atomicMax(&gmaxEnc[(size_t)sg * H2 + (u & 255)], v);
    }
  }
}

// ---------------- gpart = b3 + gmax @ W3g^T : 256 blocks x 8 segs ----------------
__global__ __launch_bounds__(256) void gpart_kernel(
    const unsigned* __restrict__ gmaxEnc, const float* __restrict__ W3gT,
    const float* __restrict__ b3, float* __restrict__ gpartG) {
  __shared__ float gm[8 * 256];
  const int t = threadIdx.x;
  const int b = blockIdx.x;
  for (int u = t; u < 8 * 256; u += 256) gm[u] = decf(gmaxEnc[(size_t)b * 8 * 256 + u]);
  __syncthreads();
  const float bb0 = b3[t], bb1 = b3[t + 256];
  float a0[8], a1[8];
  #pragma unroll
  for (int sg = 0; sg < 8; ++sg) { a0[sg] = bb0; a1[sg] = bb1; }
  for (int c = 0; c < 256; ++c) {
    float w0 = W3gT[c * 512 + t], w1 = W3gT[c * 512 + t + 256];
    #pragma unroll
    for (int sg = 0; sg < 8; ++sg) {
      float gv = gm[sg * 256 + c];
      a0[sg] += w0 * gv; a1[sg] += w1 * gv;
    }
  }
  #pragma unroll
  for (int sg = 0; sg < 8; ++sg) {
    size_t s = (size_t)b * 8 + sg;
    gpartG[s * 512 + t] = a0[sg];
    gpartG[s * 512 + t + 256] = a1[sg];
  }
}

__global__ void finalize_kernel(const unsigned* __restrict__ enc, float* __restrict__ out) {
  int i = blockIdx.x * 256 + threadIdx.x;
  if (i < NSEG * EE) out[i] = decf(enc[i]);
}

// ---------------- main v5: quarter-split N -> LDS 54.5KB -> 3 blocks/CU ----------
// Per quarter q: L3 (64x128, 1 ntile/wave, K=256) -> y1Q (16KB) -> L4 K-slice
// (ksg=q*4+ks). Every output element's MFMA K-order is ksg-ascending, identical
// to main_v2 -> bit-identical numerics. Weight traffic unchanged.
__global__ __launch_bounds__(512, 6) void main_v5(
    const int* __restrict__ segp, const ushort* __restrict__ hG,
    const ushort* __restrict__ W3hP, const ushort* __restrict__ W4P,
    const float* __restrict__ gpartG, const float* __restrict__ b4,
    unsigned* __restrict__ out_enc) {
  __shared__ __align__(16) ushort hsE[MT * 256];    // 32 KB
  __shared__ __align__(16) ushort y1Q[16 * GS];     // 16 KB (overlay: obuf)
  __shared__ float gpartL[MAXL2 * 128];             // 5 KB
  __shared__ int segdL[MT];
  __shared__ int s_loS, nlocS;

  const int t = threadIdx.x;
  const int w = t >> 6;
  const int l = t & 63;
  const int mbeg = blockIdx.x * MT;

  unsigned* obuf = (unsigned*)y1Q;

  // ---- stage hsE (linear 32KB copy) + segdL ----
  {
    const size_t tb = (size_t)blockIdx.x * (MT * 256);
    #pragma unroll
    for (int i = 0; i < 4; ++i)
      *(uint4*)&hsE[(size_t)(i * 512 + t) * 8] = *(const uint4*)&hG[tb + (size_t)(i * 512 + t) * 8];
  }
  if (t < MT) segdL[t] = segp[mbeg + t];
  __syncthreads();
  if (t == 0) {
    s_loS = segdL[0];
    nlocS = segdL[MT - 1] - segdL[0] + 1;
  }
  __syncthreads();
  const int s_lo = s_loS;
  const int nloc = nlocS;
  const bool fb = (nloc > MAXL2);

  float b4v[3];
  #pragma unroll
  for (int ni = 0; ni < 3; ++ni) b4v[ni] = b4[w * 48 + ni * 16 + (l & 15)];

  f32x4 acc4[MI_N][3];
  #pragma unroll
  for (int mi = 0; mi < MI_N; ++mi)
    #pragma unroll
    for (int ni = 0; ni < 3; ++ni)
      acc4[mi][ni] = (f32x4){0.f, 0.f, 0.f, 0.f};

  const int colq = w * 16 + (l & 15);   // this thread's L3 output column (within quarter)

  #pragma unroll
  for (int q = 0; q < 4; ++q) {
    // stage this quarter's gpart columns (independent of L3; completes at barrier)
    if (!fb) {
      for (int u = t; u < nloc * 128; u += 512)
        gpartL[u] = gpartG[(size_t)(s_lo + (u >> 7)) * 512 + q * 128 + (u & 127)];
    }

    // ---- L3 quarter: wave w -> 1 ntile (16 cols), K=256 ----
    f32x4 acc3[MI_N];
    #pragma unroll
    for (int mi = 0; mi < MI_N; ++mi) acc3[mi] = (f32x4){0.f, 0.f, 0.f, 0.f};
    #pragma unroll
    for (int ks = 0; ks < 8; ++ks) {
      short8 b0 = *(const short8*)&W3hP[(size_t)((ks * 32 + q * 8 + w) * 64 + l) * 8];
      #pragma unroll
      for (int mi = 0; mi < MI_N; ++mi) {
        short8 a = *(const short8*)&hsE[(ks * 4 + (l >> 4)) * GS + (mi * 16 + (l & 15)) * 8];
        acc3[mi] = __builtin_amdgcn_mfma_f32_16x16x32_bf16(a, b0, acc3[mi], 0, 0, 0);
      }
    }
    __syncthreads();   // gpartL staged; y1Q free (prev quarter's L4 done)

    // ---- bias(gpart) + relu -> y1Q ----
    #pragma unroll
    for (int mi = 0; mi < MI_N; ++mi) {
      #pragma unroll
      for (int r = 0; r < 4; ++r) {
        int row = mi * 16 + (l >> 4) * 4 + r;
        int sg = segdL[row];
        float bias = fb ? gpartG[(size_t)sg * 512 + q * 128 + colq]
                        : gpartL[(sg - s_lo) * 128 + colq];
        float v = fmaxf(acc3[mi][r] + bias, 0.f);
        y1Q[(colq >> 3) * GS + row * 8 + (colq & 7)] = f2bf(v);
      }
    }
    __syncthreads();   // y1Q ready

    // ---- L4 K-slice for this quarter: ksg = q*4 + ks ----
    #pragma unroll
    for (int ks = 0; ks < 4; ++ks) {
      int ksg = q * 4 + ks;
      short8 d0 = *(const short8*)&W4P[(size_t)((ksg * 24 + w * 3 + 0) * 64 + l) * 8];
      short8 d1 = *(const short8*)&W4P[(size_t)((ksg * 24 + w * 3 + 1) * 64 + l) * 8];
      short8 d2 = *(const short8*)&W4P[(size_t)((ksg * 24 + w * 3 + 2) * 64 + l) * 8];
      #pragma unroll
      for (int mi = 0; mi < MI_N; ++mi) {
        short8 a = *(const short8*)&y1Q[(ks * 4 + (l >> 4)) * GS + (mi * 16 + (l & 15)) * 8];
        acc4[mi][0] = __builtin_amdgcn_mfma_f32_16x16x32_bf16(a, d0, acc4[mi][0], 0, 0, 0);
        acc4[mi][1] = __builtin_amdgcn_mfma_f32_16x16x32_bf16(a, d1, acc4[mi][1], 0, 0, 0);
        acc4[mi][2] = __builtin_amdgcn_mfma_f32_16x16x32_bf16(a, d2, acc4[mi][2], 0, 0, 0);
      }
    }
    __syncthreads();   // L4 done reading y1Q (next quarter / obuf reuse)
  }

  // ---- epilogue: merged 4-row atomic when rows share a segment ----
  if (!fb) {
    for (int u = t; u < nloc * EE; u += 512) obuf[u] = ENCNI;   // <= 15360B of 16KB
    __syncthreads();
    #pragma unroll
    for (int mi = 0; mi < MI_N; ++mi) {
      int rbase = mi * 16 + (l >> 4) * 4;
      int sg0 = segdL[rbase], sg3 = segdL[rbase + 3];
      #pragma unroll
      for (int ni = 0; ni < 3; ++ni) {
        int col = w * 48 + ni * 16 + (l & 15);
        if (sg0 == sg3) {
          float m4 = fmaxf(fmaxf(acc4[mi][ni][0], acc4[mi][ni][1]),
                           fmaxf(acc4[mi][ni][2], acc4[mi][ni][3]));
          atomicMax(&obuf[(sg0 - s_lo) * EE + col], encf(m4 + b4v[ni]));
        } else {
          #pragma unroll
          for (int r = 0; r < 4; ++r)
            atomicMax(&obuf[(segdL[rbase + r] - s_lo) * EE + col],
                      encf(acc4[mi][ni][r] + b4v[ni]));
        }
      }
    }
    __syncthreads();
    for (int u = t; u < nloc * EE; u += 512) {
      unsigned e = obuf[u];
      if (e != ENCNI)
        atomicMax(&out_enc[(size_t)(s_lo + u / EE) * EE + (u % EE)], e);
    }
  } else {
    #pragma unroll
    for (int mi = 0; mi < MI_N; ++mi)
      #pragma unroll
      for (int ni = 0; ni < 3; ++ni) {
        int col = w * 48 + ni * 16 + (l & 15);
        #pragma unroll
        for (int r = 0; r < 4; ++r) {
          int row = mi * 16 + (l >> 4) * 4 + r;
          unsigned e = encf(acc4[mi][ni][r] + b4v[ni]);
          atomicMax(&out_enc[(size_t)segdL[row] * EE + col], e);
        }
      }
  }
}

// ---------------- fallback main (R8-validated, x-based; only if ws too small) ----
__global__ __launch_bounds__(512, 4) void main_kernel(
    const float* __restrict__ x, const int* __restrict__ perm,
    const int* __restrict__ segp,
    const float* __restrict__ W12, const float* __restrict__ b12,
    const ushort* __restrict__ W3hP, const ushort* __restrict__ W4P,
    const float* __restrict__ gpartG, const float* __restrict__ b4,
    unsigned* __restrict__ out_enc) {
  __shared__ __align__(16) ushort hsE[MT * 256];
  __shared__ __align__(16) ushort regB[MT * 256];
  __shared__ float gpartL[MAXL * 256];
  __shared__ int segdL[MT];
  __shared__ int s_loS, nlocS;

  const int t = threadIdx.x;
  const int w = t >> 6;
  const int l = t & 63;
  const int mbeg = blockIdx.x * MT;
  const int nvalid = min(MT, NPTS - mbeg);

  float* xsF  = (float*)regB;
  float* W12s = xsF + 704;
  float* b12s = W12s + 2816;
  ushort* y1E = regB;
  unsigned* obuf = (unsigned*)regB;

  for (int u = t; u < MT * NFEAT; u += 512) {
    int p = u / NFEAT, f = u - p * NFEAT;
    xsF[u] = (p < nvalid) ? x[(size_t)perm[mbeg + p] * NFEAT + f] : 0.f;
  }
  for (int u = t; u < 2816; u += 512) W12s[u] = W12[u];
  if (t < 256) b12s[t] = b12[t];
  if (t < MT) segdL[t] = (t < nvalid) ? segp[mbeg + t] : 0;
  __syncthreads();
  if (t == 0) {
    s_loS = segdL[0];
    nlocS = segdL[nvalid - 1] - segdL[0] + 1;
  }
  __syncthreads();
  const int s_lo = s_loS;
  const int nloc = nlocS;
  const bool fb = (nloc > MAXL);
  if (t < MT && t >= nvalid) segdL[t] = s_lo;

  #pragma unroll
  for (int i = 0; i < 4; ++i) {
    int gran = i * 8 + w;
    int cb = gran * 8;
    int row = l;
    uint4 pkt = {0, 0, 0, 0};
    if (row < nvalid) {
      float acc[8];
      #pragma unroll
      for (int cj = 0; cj < 8; ++cj) acc[cj] = b12s[cb + cj];
      #pragma unroll
      for (int f = 0; f < NFEAT; ++f) {
        float xv = xsF[row * NFEAT + f];
        #pragma unroll
        for (int cj = 0; cj < 8; ++cj) acc[cj] += W12s[(cb + cj) * NFEAT + f] * xv;
      }
      pkt.x = (unsigned)f2bf(acc[0]) | ((unsigned)f2bf(acc[1]) << 16);
      pkt.y = (unsigned)f2bf(acc[2]) | ((unsigned)f2bf(acc[3]) << 16);
      pkt.z = (unsigned)f2bf(acc[4]) | ((unsigned)f2bf(acc[5]) << 16);
      pkt.w = (unsigned)f2bf(acc[6]) | ((unsigned)f2bf(acc[7]) << 16);
    }
    *(uint4*)&hsE[gran * GS + row * 8] = pkt;
  }
  __syncthreads();

  float b4v[3];
  #pragma unroll
  for (int ni = 0; ni < 3; ++ni) b4v[ni] = b4[w * 48 + ni * 16 + (l & 15)];

  f32x4 acc4[MI_N][3];
  #pragma unroll
  for (int mi = 0; mi < MI_N; ++mi)
    #pragma unroll
    for (int ni = 0; ni < 3; ++ni)
      acc4[mi][ni] = (f32x4){0.f, 0.f, 0.f, 0.f};

  #pragma unroll
  for (int hf = 0; hf < 2; ++hf) {
    if (!fb) {
      for (int u = t; u < nloc * 256; u += 512) {
        int sg = u >> 8, c = u & 255;
        gpartL[u] = gpartG[(size_t)(s_lo + sg) * 512 + hf * 256 + c];
      }
    }

    f32x4 acc3[MI_N][2];
    #pragma unroll
    for (int mi = 0; mi < MI_N; ++mi)
      #pragma unroll
      for (int ni = 0; ni < 2; ++ni)
        acc3[mi][ni] = (f32x4){0.f, 0.f, 0.f, 0.f};

    #pragma unroll
    for (int ks = 0; ks < 8; ++ks) {
      short8 b0 = *(const short8*)&W3hP[(size_t)((ks * 32 + hf * 16 + w * 2 + 0) * 64 + l) * 8];
      short8 b1 = *(const short8*)&W3hP[(size_t)((ks * 32 + hf * 16 + w * 2 + 1) * 64 + l) * 8];
      #pragma unroll
      for (int mi = 0; mi < MI_N; ++mi) {
        short8 a = *(const short8*)&hsE[(ks * 4 + (l >> 4)) * GS + (mi * 16 + (l & 15)) * 8];
        acc3[mi][0] = __builtin_amdgcn_mfma_f32_16x16x32_bf16(a, b0, acc3[mi][0], 0, 0, 0);
        acc3[mi][1] = __builtin_amdgcn_mfma_f32_16x16x32_bf16(a, b1, acc3[mi][1], 0, 0, 0);
      }
    }
    __syncthreads();

    #pragma unroll
    for (int mi = 0; mi < MI_N; ++mi)
      #pragma unroll
      for (int ni = 0; ni < 2; ++ni) {
        int colh = w * 32 + ni * 16 + (l & 15);
        #pragma unroll
        for (int r = 0; r < 4; ++r) {
          int row = mi * 16 + (l >> 4) * 4 + r;
          int sg = segdL[row];
          float bias = fb ? gpartG[(size_t)sg * 512 + hf * 256 + colh]
                          : gpartL[(sg - s_lo) * 256 + colh];
          float v = fmaxf(acc3[mi][ni][r] + bias, 0.f);
          y1E[(colh >> 3) * GS + row * 8 + (colh & 7)] = f2bf(v);
        }
      }
    __syncthreads();

    #pragma unroll
    for (int ks = 0; ks < 8; ++ks) {
      short8 d0 = *(const short8*)&W4P[(size_t)(((hf * 8 + ks) * 24 + w * 3 + 0) * 64 + l) * 8];
      short8 d1 = *(const short8*)&W4P[(size_t)(((hf * 8 + ks) * 24 + w * 3 + 1) * 64 + l) * 8];
      short8 d2 = *(const short8*)&W4P[(size_t)(((hf * 8 + ks) * 24 + w * 3 + 2) * 64 + l) * 8];
      #pragma unroll
      for (int mi = 0; mi < MI_N; ++mi) {
        short8 a = *(const short8*)&y1E[(ks * 4 + (l >> 4)) * GS + (mi * 16 + (l & 15)) * 8];
        acc4[mi][0] = __builtin_amdgcn_mfma_f32_16x16x32_bf16(a, d0, acc4[mi][0], 0, 0, 0);
        acc4[mi][1] = __builtin_amdgcn_mfma_f32_16x16x32_bf16(a, d1, acc4[mi][1], 0, 0, 0);
        acc4[mi][2] = __builtin_amdgcn_mfma_f32_16x16x32_bf16(a, d2, acc4[mi][2], 0, 0, 0);
      }
    }
    __syncthreads();
  }

  if (!fb) {
    for (int u = t; u < nloc * EE; u += 512) obuf[u] = ENCNI;
    __syncthreads();
    #pragma unroll
    for (int mi = 0; mi < MI_N; ++mi)
      #pragma unroll
      for (int ni = 0; ni < 3; ++ni) {
        int col = w * 48 + ni * 16 + (l & 15);
        #pragma unroll
        for (int r = 0; r < 4; ++r) {
          int row = mi * 16 + (l >> 4) * 4 + r;
          if (row < nvalid) {
            unsigned e = encf(acc4[mi][ni][r] + b4v[ni]);
            atomicMax(&obuf[(segdL[row] - s_lo) * EE + col], e);
          }
        }
      }
    __syncthreads();
    for (int u = t; u < nloc * EE; u += 512) {
      unsigned e = obuf[u];
      if (e != ENCNI)
        atomicMax(&out_enc[(size_t)(s_lo + u / EE) * EE + (u % EE)], e);
    }
  } else {
    #pragma unroll
    for (int mi = 0; mi < MI_N; ++mi)
      #pragma unroll
      for (int ni = 0; ni < 3; ++ni) {
        int col = w * 48 + ni * 16 + (l & 15);
        #pragma unroll
        for (int r = 0; r < 4; ++r) {
          int row = mi * 16 + (l >> 4) * 4 + r;
          if (row < nvalid) {
            unsigned e = encf(acc4[mi][ni][r] + b4v[ni]);
            atomicMax(&out_enc[(size_t)segdL[row] * EE + col], e);
          }
        }
      }
  }
}

extern "C" void kernel_launch(void* const* d_in, const int* in_sizes, int n_in,
                              void* d_out, int out_size, void* d_ws, size_t ws_size,
                              hipStream_t stream) {
  (void)in_sizes; (void)n_in; (void)out_size;
  const float* x    = (const float*)d_in[0];
  const int*   sidx = (const int*)d_in[1];
  const float* W1   = (const float*)d_in[2];
  const float* b1   = (const float*)d_in[3];
  const float* W2   = (const float*)d_in[4];
  const float* b2   = (const float*)d_in[5];
  const float* W3   = (const float*)d_in[6];
  const float* b3   = (const float*)d_in[7];
  const float* W4   = (const float*)d_in[8];
  const float* b4   = (const float*)d_in[9];
  float* out = (float*)d_out;

  char* ws = (char*)d_ws;
  size_t off = 0;
  auto alloc = [&](size_t bytes) {
    void* p = ws + off;
    off = (off + bytes + 255) & ~(size_t)255;
    return p;
  };
  int*      counts  = (int*)alloc(NSEG * 4);   // counts+cursor contiguous for one memset
  int*      cursor  = (int*)alloc(NSEG * 4);
  int*      offs    = (int*)alloc((NSEG + 1) * 4);
  int*      perm    = (int*)alloc((size_t)NPTS * 4);
  int*      segp    = (int*)alloc((size_t)NPTS * 4);
  float*    W12     = (float*)alloc(H2 * NFEAT * 4);
  float*    b12     = (float*)alloc(H2 * 4);
  float*    W3gT    = (float*)alloc((size_t)H2 * H3 * 4);
  ushort*   W3hP    = (ushort*)alloc((size_t)131072 * 2);
  ushort*   W4P     = (ushort*)alloc((size_t)196608 * 2);
  unsigned* gmaxEnc = (unsigned*)alloc((size_t)NSEG * H2 * 4);
  float*    gpartG  = (float*)alloc((size_t)NSEG * H3 * 4);
  unsigned* out_enc = (unsigned*)alloc((size_t)NSEG * EE * 4);
  ushort*   hG      = (ushort*)alloc((size_t)NPTS * 256 * 2);   // 204.8 MB
  const bool useH = (off <= ws_size);                           // deterministic

  hipMemsetAsync(counts, 0, (size_t)NSEG * 8, stream);
  prep_init<<<(NSEG * EE + 255) / 256, 256, 0, stream>>>(W1, b1, W2, b2, W3, W4, sidx,
                                                         W12, b12, W3gT, W3hP, W4P,
                                                         counts, gmaxEnc, out_enc);
  scan_kernel<<<1, 1024, 0, stream>>>(counts, offs);
  scatter_kernel<<<(NPTS + 255) / 256, 256, 0, stream>>>(sidx, offs, cursor, perm, segp);
  if (useH) {
    gmax_kernel<true><<<(NPTS + RSEG - 1) / RSEG, 512, 0, stream>>>(x, perm, segp, W12, b12, gmaxEnc, hG);
    gpart_kernel<<<NSEG / 8, 256, 0, stream>>>(gmaxEnc, W3gT, b3, gpartG);
    main_v5<<<NPTS / MT, 512, 0, stream>>>(segp, hG, W3hP, W4P, gpartG, b4, out_enc);
  } else {
    gmax_kernel<false><<<(NPTS + RSEG - 1) / RSEG, 512, 0, stream>>>(x, perm, segp, W12, b12, gmaxEnc, hG);
    gpart_kernel<<<NSEG / 8, 256, 0, stream>>>(gmaxEnc, W3gT, b3, gpartG);
    main_kernel<<<NPTS / MT, 512, 0, stream>>>(x, perm, segp, W12, b12,
                                               W3hP, W4P, gpartG, b4, out_enc);
  }
  finalize_kernel<<<(NSEG * EE + 255) / 256, 256, 0, stream>>>(out_enc, out);
}

// Round 15
// 646.180 us; speedup vs baseline: 1.5161x; 1.5161x over previous
//
#include <hip/hip_runtime.h>
#include <hip/hip_bf16.h>
#include <math.h>

#define BB    4
#define NN    100000
#define NFEAT 11
#define NSP   512
#define NSEG  (BB*NSP)     // 2048
#define NPTS  (BB*NN)      // 400000
#define H2    256
#define H3    512
#define EE    384
#define MT    64           // main M-tile rows (NPTS % MT == 0)
#define GS    (MT*8)       // granule stride in ushorts
#define MI_N  (MT/16)
#define MAXL  15           // main: max distinct segments per tile
#define RSEG  512          // gmax kernel rows per block
#define MAXS  12           // gmax kernel: max distinct segments per block
#define ENCNI 0x007FFFFFu  // enc(-inf)

typedef __attribute__((ext_vector_type(8))) short short8;
typedef __attribute__((ext_vector_type(4))) float f32x4;

__device__ __forceinline__ ushort f2bf(float f) {
  unsigned u = __builtin_bit_cast(unsigned, f);
  unsigned r = (u + 0x7FFFu + ((u >> 16) & 1u)) >> 16;
  return (ushort)r;
}
__device__ __forceinline__ unsigned encf(float f) {
  unsigned u = __builtin_bit_cast(unsigned, f);
  return u ^ ((unsigned)((int)u >> 31) | 0x80000000u);
}
__device__ __forceinline__ float decf(unsigned e) {
  unsigned u = (e & 0x80000000u) ? (e ^ 0x80000000u) : ~e;
  return __builtin_bit_cast(float, u);
}

// ---------------- init enc buffers + weight prep + histogram ----------------
__global__ void prep_init(const float* __restrict__ W1, const float* __restrict__ b1,
                          const float* __restrict__ W2, const float* __restrict__ b2,
                          const float* __restrict__ W3, const float* __restrict__ W4,
                          const int* __restrict__ sidx,
                          float* __restrict__ W12, float* __restrict__ b12,
                          float* __restrict__ W3gT, ushort* __restrict__ W3hP,
                          ushort* __restrict__ W4P,
                          int* __restrict__ counts,
                          unsigned* __restrict__ gmaxEnc, unsigned* __restrict__ out_enc) {
  int u = blockIdx.x * 256 + threadIdx.x;
  if (u < NSEG * EE) out_enc[u] = ENCNI;
  if (u < NSEG * H2) gmaxEnc[u] = ENCNI;
  if (u < NPTS) {
    int seg = sidx[u] + (u / NN) * NSP;
    atomicAdd(&counts[seg], 1);
  }

  if (u < H2 * NFEAT) {
    int c = u / NFEAT, f = u - c * NFEAT;
    float acc = 0.f;
    for (int j = 0; j < 128; ++j) acc += W2[c * 128 + j] * W1[j * NFEAT + f];
    W12[u] = acc;
  } else if (u < 3072) {
    int c = u - H2 * NFEAT;
    float acc = b2[c];
    for (int j = 0; j < 128; ++j) acc += W2[c * 128 + j] * b1[j];
    b12[c] = acc;
  } else if (u < 3072 + 131072) {
    int v = u - 3072;
    int c = v >> 9, o = v & 511;
    W3gT[v] = W3[o * H3 + c];
  } else if (u < 134144 + 16384) {
    int v = u - 134144;
    int ks = v >> 11, rem = v & 2047;
    int nt = rem >> 6, l = rem & 63;
    int n = nt * 16 + (l & 15);
    #pragma unroll
    for (int j = 0; j < 8; ++j) {
      int k = ks * 32 + (l >> 4) * 8 + j;
      W3hP[(size_t)v * 8 + j] = f2bf(W3[n * H3 + H2 + k]);
    }
  } else if (u < 150528 + 24576) {
    int v = u - 150528;
    int ks = v / 1536, rem = v - ks * 1536;
    int nt = rem >> 6, l = rem & 63;
    int n = nt * 16 + (l & 15);
    #pragma unroll
    for (int j = 0; j < 8; ++j) {
      int k = ks * 32 + (l >> 4) * 8 + j;
      W4P[(size_t)v * 8 + j] = f2bf(W4[n * H3 + k]);
    }
  }
}

__global__ void scan_kernel(const int* __restrict__ counts, int* __restrict__ offs) {
  __shared__ int buf[1024];
  int t = threadIdx.x;
  int c0 = counts[2 * t], c1 = counts[2 * t + 1];
  int s = c0 + c1;
  buf[t] = s;
  __syncthreads();
  for (int d = 1; d < 1024; d <<= 1) {
    int add = (t >= d) ? buf[t - d] : 0;
    __syncthreads();
    buf[t] += add;
    __syncthreads();
  }
  int incl = buf[t];
  int excl = incl - s;
  offs[2 * t] = excl;
  offs[2 * t + 1] = excl + c0;
  if (t == 1023) offs[2048] = incl;
}

__global__ void scatter_kernel(const int* __restrict__ sidx, const int* __restrict__ offs,
                               int* __restrict__ cursor, int* __restrict__ perm,
                               int* __restrict__ segp) {
  int i = blockIdx.x * blockDim.x + threadIdx.x;
  if (i < NPTS) {
    int seg = sidx[i] + (i / NN) * NSP;
    int pos = offs[seg] + atomicAdd(&cursor[seg], 1);
    perm[pos] = i;
    segp[pos] = seg;
  }
}

// ---------------- gmax (+optional h store), validated R8/R9/R11 ----------------
template <bool STOREH>
__global__ __launch_bounds__(512) void gmax_kernel(
    const float* __restrict__ x, const int* __restrict__ perm,
    const int* __restrict__ segp,
    const float* __restrict__ W12, const float* __restrict__ b12,
    unsigned* __restrict__ gmaxEnc, ushort* __restrict__ hG) {
  __shared__ float xs[RSEG * NFEAT];
  __shared__ float W12s[H2 * NFEAT];
  __shared__ float b12s[H2];
  __shared__ int   segd[RSEG];
  __shared__ unsigned gmaxL[MAXS * H2];

  const int t = threadIdx.x;
  const int mbeg = blockIdx.x * RSEG;
  const int nvalid = min(RSEG, NPTS - mbeg);

  for (int u = t; u < RSEG * NFEAT; u += 512) {
    int p = u / NFEAT, f = u - p * NFEAT;
    xs[u] = (p < nvalid) ? x[(size_t)perm[mbeg + p] * NFEAT + f] : 0.f;
  }
  for (int u = t; u < H2 * NFEAT; u += 512) W12s[u] = W12[u];
  if (t < H2) b12s[t] = b12[t];
  segd[t] = (t < nvalid) ? segp[mbeg + t] : segp[mbeg + nvalid - 1];
  for (int u = t; u < MAXS * H2; u += 512) gmaxL[u] = ENCNI;
  __syncthreads();

  const int s_lo = segd[0];
  const int s_hi = segd[nvalid - 1];
  const bool fb = (s_hi - s_lo + 1) > MAXS;

  const int g  = t >> 4;
  const int r0 = t & 15;
  const int cb = g * 8;

  float w12r[8][NFEAT], bbr[8];
  #pragma unroll
  for (int cj = 0; cj < 8; ++cj) {
    bbr[cj] = b12s[cb + cj];
    #pragma unroll
    for (int f = 0; f < NFEAT; ++f) w12r[cj][f] = W12s[(cb + cj) * NFEAT + f];
  }

  float m[8];
  #pragma unroll
  for (int cj = 0; cj < 8; ++cj) m[cj] = -INFINITY;
  int cur = segd[r0];
  bool any = false;

  for (int k = 0; k < 32; ++k) {
    int row = r0 + k * 16;
    if (row >= nvalid) break;
    int sg = segd[row];
    if (sg != cur) {
      #pragma unroll
      for (int cj = 0; cj < 8; ++cj) {
        unsigned e = encf(m[cj]);
        if (fb) atomicMax(&gmaxEnc[(size_t)cur * H2 + cb + cj], e);
        else    atomicMax(&gmaxL[(cur - s_lo) * H2 + cb + cj], e);
      }
      cur = sg;
      #pragma unroll
      for (int cj = 0; cj < 8; ++cj) m[cj] = -INFINITY;
    }
    float acc[8];
    #pragma unroll
    for (int cj = 0; cj < 8; ++cj) acc[cj] = bbr[cj];
    #pragma unroll
    for (int f = 0; f < NFEAT; ++f) {
      float xv = xs[row * NFEAT + f];
      #pragma unroll
      for (int cj = 0; cj < 8; ++cj) acc[cj] += w12r[cj][f] * xv;
    }
    if (STOREH) {
      uint4 pkt;
      pkt.x = (unsigned)f2bf(acc[0]) | ((unsigned)f2bf(acc[1]) << 16);
      pkt.y = (unsigned)f2bf(acc[2]) | ((unsigned)f2bf(acc[3]) << 16);
      pkt.z = (unsigned)f2bf(acc[4]) | ((unsigned)f2bf(acc[5]) << 16);
      pkt.w = (unsigned)f2bf(acc[6]) | ((unsigned)f2bf(acc[7]) << 16);
      int pt = mbeg + row;
      *(uint4*)&hG[(size_t)(pt >> 6) * 16384 + ((size_t)g * 64 + (pt & 63)) * 8] = pkt;
    }
    #pragma unroll
    for (int cj = 0; cj < 8; ++cj) m[cj] = fmaxf(m[cj], acc[cj]);
    any = true;
  }
  if (any) {
    #pragma unroll
    for (int cj = 0; cj < 8; ++cj) {
      unsigned e = encf(m[cj]);
      if (fb) atomicMax(&gmaxEnc[(size_t)cur * H2 + cb + cj], e);
      else    atomicMax(&gmaxL[(cur - s_lo) * H2 + cb + cj], e);
    }
  }

  __syncthreads();
  if (!fb) {
    int nloc = s_hi - s_lo + 1;
    for (int u = t; u < nloc * H2; u += 512) {
      int sg = s_lo + (u >> 8);
      unsigned v = gmaxL[u];
      if (sg > s_lo && sg < s_hi) gmaxEnc[(size_t)sg * H2 + (u & 255)] = v;
      else atomicMax(&gmaxEnc[(size_t)sg * H2 + (u & 255)], v);
    }
  }
}

// ---------------- gpart = b3 + gmax @ W3g^T : 256 blocks x 8 segs ----------------
__global__ __launch_bounds__(256) void gpart_kernel(
    const unsigned* __restrict__ gmaxEnc, const float* __restrict__ W3gT,
    const float* __restrict__ b3, float* __restrict__ gpartG) {
  __shared__ float gm[8 * 256];
  const int t = threadIdx.x;
  const int b = blockIdx.x;
  for (int u = t; u < 8 * 256; u += 256) gm[u] = decf(gmaxEnc[(size_t)b * 8 * 256 + u]);
  __syncthreads();
  const float bb0 = b3[t], bb1 = b3[t + 256];
  float a0[8], a1[8];
  #pragma unroll
  for (int sg = 0; sg < 8; ++sg) { a0[sg] = bb0; a1[sg] = bb1; }
  for (int c = 0; c < 256; ++c) {
    float w0 = W3gT[c * 512 + t], w1 = W3gT[c * 512 + t + 256];
    #pragma unroll
    for (int sg = 0; sg < 8; ++sg) {
      float gv = gm[sg * 256 + c];
      a0[sg] += w0 * gv; a1[sg] += w1 * gv;
    }
  }
  #pragma unroll
  for (int sg = 0; sg < 8; ++sg) {
    size_t s = (size_t)b * 8 + sg;
    gpartG[s * 512 + t] = a0[sg];
    gpartG[s * 512 + t + 256] = a1[sg];
  }
}

__global__ void finalize_kernel(const unsigned* __restrict__ enc, float* __restrict__ out) {
  int i = blockIdx.x * 256 + threadIdx.x;
  if (i < NSEG * EE) out[i] = decf(enc[i]);
}

// ---------------- main v2 (exact R9/R11-validated kernel) ----------------
__global__ __launch_bounds__(512, 4) void main_v2(
    const int* __restrict__ segp, const ushort* __restrict__ hG,
    const ushort* __restrict__ W3hP, const ushort* __restrict__ W4P,
    const float* __restrict__ gpartG, const float* __restrict__ b4,
    unsigned* __restrict__ out_enc) {
  __shared__ __align__(16) ushort hsE[MT * 256];
  __shared__ __align__(16) ushort regB[MT * 256];
  __shared__ float gpartL[MAXL * 256];
  __shared__ int segdL[MT];
  __shared__ int s_loS, nlocS;

  const int t = threadIdx.x;
  const int w = t >> 6;
  const int l = t & 63;
  const int mbeg = blockIdx.x * MT;

  ushort* y1E = regB;
  unsigned* obuf = (unsigned*)regB;

  {
    const size_t tb = (size_t)blockIdx.x * (MT * 256);
    #pragma unroll
    for (int i = 0; i < 4; ++i)
      *(uint4*)&hsE[(size_t)(i * 512 + t) * 8] = *(const uint4*)&hG[tb + (size_t)(i * 512 + t) * 8];
  }
  if (t < MT) segdL[t] = segp[mbeg + t];
  __syncthreads();
  if (t == 0) {
    s_loS = segdL[0];
    nlocS = segdL[MT - 1] - segdL[0] + 1;
  }
  __syncthreads();
  const int s_lo = s_loS;
  const int nloc = nlocS;
  const bool fb = (nloc > MAXL);

  float b4v[3];
  #pragma unroll
  for (int ni = 0; ni < 3; ++ni) b4v[ni] = b4[w * 48 + ni * 16 + (l & 15)];

  f32x4 acc4[MI_N][3];
  #pragma unroll
  for (int mi = 0; mi < MI_N; ++mi)
    #pragma unroll
    for (int ni = 0; ni < 3; ++ni)
      acc4[mi][ni] = (f32x4){0.f, 0.f, 0.f, 0.f};

  #pragma unroll
  for (int hf = 0; hf < 2; ++hf) {
    if (!fb) {
      for (int u = t; u < nloc * 256; u += 512) {
        int sg = u >> 8, c = u & 255;
        gpartL[u] = gpartG[(size_t)(s_lo + sg) * 512 + hf * 256 + c];
      }
    }

    f32x4 acc3[MI_N][2];
    #pragma unroll
    for (int mi = 0; mi < MI_N; ++mi)
      #pragma unroll
      for (int ni = 0; ni < 2; ++ni)
        acc3[mi][ni] = (f32x4){0.f, 0.f, 0.f, 0.f};

    {
      short8 bcur[2][2], bnxt[2][2];
      #pragma unroll
      for (int c2 = 0; c2 < 2; ++c2)
        #pragma unroll
        for (int ni = 0; ni < 2; ++ni)
          bcur[c2][ni] = *(const short8*)&W3hP[(size_t)(((c2) * 32 + hf * 16 + w * 2 + ni) * 64 + l) * 8];
      #pragma unroll
      for (int kc = 0; kc < 4; ++kc) {
        if (kc < 3) {
          #pragma unroll
          for (int c2 = 0; c2 < 2; ++c2)
            #pragma unroll
            for (int ni = 0; ni < 2; ++ni)
              bnxt[c2][ni] = *(const short8*)&W3hP[(size_t)(((kc * 2 + 2 + c2) * 32 + hf * 16 + w * 2 + ni) * 64 + l) * 8];
        }
        #pragma unroll
        for (int c2 = 0; c2 < 2; ++c2) {
          const int ks = kc * 2 + c2;
          #pragma unroll
          for (int mi = 0; mi < MI_N; ++mi) {
            short8 a = *(const short8*)&hsE[(ks * 4 + (l >> 4)) * GS + (mi * 16 + (l & 15)) * 8];
            acc3[mi][0] = __builtin_amdgcn_mfma_f32_16x16x32_bf16(a, bcur[c2][0], acc3[mi][0], 0, 0, 0);
            acc3[mi][1] = __builtin_amdgcn_mfma_f32_16x16x32_bf16(a, bcur[c2][1], acc3[mi][1], 0, 0, 0);
          }
        }
        if (kc < 3) {
          #pragma unroll
          for (int c2 = 0; c2 < 2; ++c2)
            #pragma unroll
            for (int ni = 0; ni < 2; ++ni)
              bcur[c2][ni] = bnxt[c2][ni];
        }
      }
    }
    __syncthreads();

    #pragma unroll
    for (int mi = 0; mi < MI_N; ++mi)
      #pragma unroll
      for (int ni = 0; ni < 2; ++ni) {
        int colh = w * 32 + ni * 16 + (l & 15);
        #pragma unroll
        for (int r = 0; r < 4; ++r) {
          int row = mi * 16 + (l >> 4) * 4 + r;
          int sg = segdL[row];
          float bias = fb ? gpartG[(size_t)sg * 512 + hf * 256 + colh]
                          : gpartL[(sg - s_lo) * 256 + colh];
          float v = fmaxf(acc3[mi][ni][r] + bias, 0.f);
          y1E[(colh >> 3) * GS + row * 8 + (colh & 7)] = f2bf(v);
        }
      }
    __syncthreads();

    {
      short8 bcur[2][3], bnxt[2][3];
      #pragma unroll
      for (int c2 = 0; c2 < 2; ++c2)
        #pragma unroll
        for (int ni = 0; ni < 3; ++ni)
          bcur[c2][ni] = *(const short8*)&W4P[(size_t)(((hf * 8 + c2) * 24 + w * 3 + ni) * 64 + l) * 8];
      #pragma unroll
      for (int kc = 0; kc < 4; ++kc) {
        if (kc < 3) {
          #pragma unroll
          for (int c2 = 0; c2 < 2; ++c2)
            #pragma unroll
            for (int ni = 0; ni < 3; ++ni)
              bnxt[c2][ni] = *(const short8*)&W4P[(size_t)(((hf * 8 + kc * 2 + 2 + c2) * 24 + w * 3 + ni) * 64 + l) * 8];
        }
        #pragma unroll
        for (int c2 = 0; c2 < 2; ++c2) {
          const int ks = kc * 2 + c2;
          #pragma unroll
          for (int mi = 0; mi < MI_N; ++mi) {
            short8 a = *(const short8*)&y1E[(ks * 4 + (l >> 4)) * GS + (mi * 16 + (l & 15)) * 8];
            acc4[mi][0] = __builtin_amdgcn_mfma_f32_16x16x32_bf16(a, bcur[c2][0], acc4[mi][0], 0, 0, 0);
            acc4[mi][1] = __builtin_amdgcn_mfma_f32_16x16x32_bf16(a, bcur[c2][1], acc4[mi][1], 0, 0, 0);
            acc4[mi][2] = __builtin_amdgcn_mfma_f32_16x16x32_bf16(a, bcur[c2][2], acc4[mi][2], 0, 0, 0);
          }
        }
        if (kc < 3) {
          #pragma unroll
          for (int c2 = 0; c2 < 2; ++c2)
            #pragma unroll
            for (int ni = 0; ni < 3; ++ni)
              bcur[c2][ni] = bnxt[c2][ni];
        }
      }
    }
    __syncthreads();
  }

  if (!fb) {
    for (int u = t; u < nloc * EE; u += 512) obuf[u] = ENCNI;
    __syncthreads();
    #pragma unroll
    for (int mi = 0; mi < MI_N; ++mi) {
      int rbase = mi * 16 + (l >> 4) * 4;
      int sg0 = segdL[rbase], sg3 = segdL[rbase + 3];
      #pragma unroll
      for (int ni = 0; ni < 3; ++ni) {
        int col = w * 48 + ni * 16 + (l & 15);
        if (sg0 == sg3) {
          float m4 = fmaxf(fmaxf(acc4[mi][ni][0], acc4[mi][ni][1]),
                           fmaxf(acc4[mi][ni][2], acc4[mi][ni][3]));
          atomicMax(&obuf[(sg0 - s_lo) * EE + col], encf(m4 + b4v[ni]));
        } else {
          #pragma unroll
          for (int r = 0; r < 4; ++r)
            atomicMax(&obuf[(segdL[rbase + r] - s_lo) * EE + col],
                      encf(acc4[mi][ni][r] + b4v[ni]));
        }
      }
    }
    __syncthreads();
    for (int u = t; u < nloc * EE; u += 512) {
      unsigned e = obuf[u];
      if (e != ENCNI)
        atomicMax(&out_enc[(size_t)(s_lo + u / EE) * EE + (u % EE)], e);
    }
  } else {
    #pragma unroll
    for (int mi = 0; mi < MI_N; ++mi)
      #pragma unroll
      for (int ni = 0; ni < 3; ++ni) {
        int col = w * 48 + ni * 16 + (l & 15);
        #pragma unroll
        for (int r = 0; r < 4; ++r) {
          int row = mi * 16 + (l >> 4) * 4 + r;
          unsigned e = encf(acc4[mi][ni][r] + b4v[ni]);
          atomicMax(&out_enc[(size_t)segdL[row] * EE + col], e);
        }
      }
  }
}

// ---------------- fallback main (R8-validated, x-based; only if ws too small) ----
__global__ __launch_bounds__(512, 4) void main_kernel(
    const float* __restrict__ x, const int* __restrict__ perm,
    const int* __restrict__ segp,
    const float* __restrict__ W12, const float* __restrict__ b12,
    const ushort* __restrict__ W3hP, const ushort* __restrict__ W4P,
    const float* __restrict__ gpartG, const float* __restrict__ b4,
    unsigned* __restrict__ out_enc) {
  __shared__ __align__(16) ushort hsE[MT * 256];
  __shared__ __align__(16) ushort regB[MT * 256];
  __shared__ float gpartL[MAXL * 256];
  __shared__ int segdL[MT];
  __shared__ int s_loS, nlocS;

  const int t = threadIdx.x;
  const int w = t >> 6;
  const int l = t & 63;
  const int mbeg = blockIdx.x * MT;
  const int nvalid = min(MT, NPTS - mbeg);

  float* xsF  = (float*)regB;
  float* W12s = xsF + 704;
  float* b12s = W12s + 2816;
  ushort* y1E = regB;
  unsigned* obuf = (unsigned*)regB;

  for (int u = t; u < MT * NFEAT; u += 512) {
    int p = u / NFEAT, f = u - p * NFEAT;
    xsF[u] = (p < nvalid) ? x[(size_t)perm[mbeg + p] * NFEAT + f] : 0.f;
  }
  for (int u = t; u < 2816; u += 512) W12s[u] = W12[u];
  if (t < 256) b12s[t] = b12[t];
  if (t < MT) segdL[t] = (t < nvalid) ? segp[mbeg + t] : 0;
  __syncthreads();
  if (t == 0) {
    s_loS = segdL[0];
    nlocS = segdL[nvalid - 1] - segdL[0] + 1;
  }
  __syncthreads();
  const int s_lo = s_loS;
  const int nloc = nlocS;
  const bool fb = (nloc > MAXL);
  if (t < MT && t >= nvalid) segdL[t] = s_lo;

  #pragma unroll
  for (int i = 0; i < 4; ++i) {
    int gran = i * 8 + w;
    int cb = gran * 8;
    int row = l;
    uint4 pkt = {0, 0, 0, 0};
    if (row < nvalid) {
      float acc[8];
      #pragma unroll
      for (int cj = 0; cj < 8; ++cj) acc[cj] = b12s[cb + cj];
      #pragma unroll
      for (int f = 0; f < NFEAT; ++f) {
        float xv = xsF[row * NFEAT + f];
        #pragma unroll
        for (int cj = 0; cj < 8; ++cj) acc[cj] += W12s[(cb + cj) * NFEAT + f] * xv;
      }
      pkt.x = (unsigned)f2bf(acc[0]) | ((unsigned)f2bf(acc[1]) << 16);
      pkt.y = (unsigned)f2bf(acc[2]) | ((unsigned)f2bf(acc[3]) << 16);
      pkt.z = (unsigned)f2bf(acc[4]) | ((unsigned)f2bf(acc[5]) << 16);
      pkt.w = (unsigned)f2bf(acc[6]) | ((unsigned)f2bf(acc[7]) << 16);
    }
    *(uint4*)&hsE[gran * GS + row * 8] = pkt;
  }
  __syncthreads();

  float b4v[3];
  #pragma unroll
  for (int ni = 0; ni < 3; ++ni) b4v[ni] = b4[w * 48 + ni * 16 + (l & 15)];

  f32x4 acc4[MI_N][3];
  #pragma unroll
  for (int mi = 0; mi < MI_N; ++mi)
    #pragma unroll
    for (int ni = 0; ni < 3; ++ni)
      acc4[mi][ni] = (f32x4){0.f, 0.f, 0.f, 0.f};

  #pragma unroll
  for (int hf = 0; hf < 2; ++hf) {
    if (!fb) {
      for (int u = t; u < nloc * 256; u += 512) {
        int sg = u >> 8, c = u & 255;
        gpartL[u] = gpartG[(size_t)(s_lo + sg) * 512 + hf * 256 + c];
      }
    }

    f32x4 acc3[MI_N][2];
    #pragma unroll
    for (int mi = 0; mi < MI_N; ++mi)
      #pragma unroll
      for (int ni = 0; ni < 2; ++ni)
        acc3[mi][ni] = (f32x4){0.f, 0.f, 0.f, 0.f};

    #pragma unroll
    for (int ks = 0; ks < 8; ++ks) {
      short8 b0 = *(const short8*)&W3hP[(size_t)((ks * 32 + hf * 16 + w * 2 + 0) * 64 + l) * 8];
      short8 b1 = *(const short8*)&W3hP[(size_t)((ks * 32 + hf * 16 + w * 2 + 1) * 64 + l) * 8];
      #pragma unroll
      for (int mi = 0; mi < MI_N; ++mi) {
        short8 a = *(const short8*)&hsE[(ks * 4 + (l >> 4)) * GS + (mi * 16 + (l & 15)) * 8];
        acc3[mi][0] = __builtin_amdgcn_mfma_f32_16x16x32_bf16(a, b0, acc3[mi][0], 0, 0, 0);
        acc3[mi][1] = __builtin_amdgcn_mfma_f32_16x16x32_bf16(a, b1, acc3[mi][1], 0, 0, 0);
      }
    }
    __syncthreads();

    #pragma unroll
    for (int mi = 0; mi < MI_N; ++mi)
      #pragma unroll
      for (int ni = 0; ni < 2; ++ni) {
        int colh = w * 32 + ni * 16 + (l & 15);
        #pragma unroll
        for (int r = 0; r < 4; ++r) {
          int row = mi * 16 + (l >> 4) * 4 + r;
          int sg = segdL[row];
          float bias = fb ? gpartG[(size_t)sg * 512 + hf * 256 + colh]
                          : gpartL[(sg - s_lo) * 256 + colh];
          float v = fmaxf(acc3[mi][ni][r] + bias, 0.f);
          y1E[(colh >> 3) * GS + row * 8 + (colh & 7)] = f2bf(v);
        }
      }
    __syncthreads();

    #pragma unroll
    for (int ks = 0; ks < 8; ++ks) {
      short8 d0 = *(const short8*)&W4P[(size_t)(((hf * 8 + ks) * 24 + w * 3 + 0) * 64 + l) * 8];
      short8 d1 = *(const short8*)&W4P[(size_t)(((hf * 8 + ks) * 24 + w * 3 + 1) * 64 + l) * 8];
      short8 d2 = *(const short8*)&W4P[(size_t)(((hf * 8 + ks) * 24 + w * 3 + 2) * 64 + l) * 8];
      #pragma unroll
      for (int mi = 0; mi < MI_N; ++mi) {
        short8 a = *(const short8*)&y1E[(ks * 4 + (l >> 4)) * GS + (mi * 16 + (l & 15)) * 8];
        acc4[mi][0] = __builtin_amdgcn_mfma_f32_16x16x32_bf16(a, d0, acc4[mi][0], 0, 0, 0);
        acc4[mi][1] = __builtin_amdgcn_mfma_f32_16x16x32_bf16(a, d1, acc4[mi][1], 0, 0, 0);
        acc4[mi][2] = __builtin_amdgcn_mfma_f32_16x16x32_bf16(a, d2, acc4[mi][2], 0, 0, 0);
      }
    }
    __syncthreads();
  }

  if (!fb) {
    for (int u = t; u < nloc * EE; u += 512) obuf[u] = ENCNI;
    __syncthreads();
    #pragma unroll
    for (int mi = 0; mi < MI_N; ++mi)
      #pragma unroll
      for (int ni = 0; ni < 3; ++ni) {
        int col = w * 48 + ni * 16 + (l & 15);
        #pragma unroll
        for (int r = 0; r < 4; ++r) {
          int row = mi * 16 + (l >> 4) * 4 + r;
          if (row < nvalid) {
            unsigned e = encf(acc4[mi][ni][r] + b4v[ni]);
            atomicMax(&obuf[(segdL[row] - s_lo) * EE + col], e);
          }
        }
      }
    __syncthreads();
    for (int u = t; u < nloc * EE; u += 512) {
      unsigned e = obuf[u];
      if (e != ENCNI)
        atomicMax(&out_enc[(size_t)(s_lo + u / EE) * EE + (u % EE)], e);
    }
  } else {
    #pragma unroll
    for (int mi = 0; mi < MI_N; ++mi)
      #pragma unroll
      for (int ni = 0; ni < 3; ++ni) {
        int col = w * 48 + ni * 16 + (l & 15);
        #pragma unroll
        for (int r = 0; r < 4; ++r) {
          int row = mi * 16 + (l >> 4) * 4 + r;
          if (row < nvalid) {
            unsigned e = encf(acc4[mi][ni][r] + b4v[ni]);
            atomicMax(&out_enc[(size_t)segdL[row] * EE + col], e);
          }
        }
      }
  }
}

extern "C" void kernel_launch(void* const* d_in, const int* in_sizes, int n_in,
                              void* d_out, int out_size, void* d_ws, size_t ws_size,
                              hipStream_t stream) {
  (void)in_sizes; (void)n_in; (void)out_size;
  const float* x    = (const float*)d_in[0];
  const int*   sidx = (const int*)d_in[1];
  const float* W1   = (const float*)d_in[2];
  const float* b1   = (const float*)d_in[3];
  const float* W2   = (const float*)d_in[4];
  const float* b2   = (const float*)d_in[5];
  const float* W3   = (const float*)d_in[6];
  const float* b3   = (const float*)d_in[7];
  const float* W4   = (const float*)d_in[8];
  const float* b4   = (const float*)d_in[9];
  float* out = (float*)d_out;

  char* ws = (char*)d_ws;
  size_t off = 0;
  auto alloc = [&](size_t bytes) {
    void* p = ws + off;
    off = (off + bytes + 255) & ~(size_t)255;
    return p;
  };
  int*      counts  = (int*)alloc(NSEG * 4);   // counts+cursor contiguous for one memset
  int*      cursor  = (int*)alloc(NSEG * 4);
  int*      offs    = (int*)alloc((NSEG + 1) * 4);
  int*      perm    = (int*)alloc((size_t)NPTS * 4);
  int*      segp    = (int*)alloc((size_t)NPTS * 4);
  float*    W12     = (float*)alloc(H2 * NFEAT * 4);
  float*    b12     = (float*)alloc(H2 * 4);
  float*    W3gT    = (float*)alloc((size_t)H2 * H3 * 4);
  ushort*   W3hP    = (ushort*)alloc((size_t)131072 * 2);
  ushort*   W4P     = (ushort*)alloc((size_t)196608 * 2);
  unsigned* gmaxEnc = (unsigned*)alloc((size_t)NSEG * H2 * 4);
  float*    gpartG  = (float*)alloc((size_t)NSEG * H3 * 4);
  unsigned* out_enc = (unsigned*)alloc((size_t)NSEG * EE * 4);
  ushort*   hG      = (ushort*)alloc((size_t)NPTS * 256 * 2);   // 204.8 MB
  const bool useH = (off <= ws_size);                           // deterministic

  hipMemsetAsync(counts, 0, (size_t)NSEG * 8, stream);
  prep_init<<<(NSEG * EE + 255) / 256, 256, 0, stream>>>(W1, b1, W2, b2, W3, W4, sidx,
                                                         W12, b12, W3gT, W3hP, W4P,
                                                         counts, gmaxEnc, out_enc);
  scan_kernel<<<1, 1024, 0, stream>>>(counts, offs);
  scatter_kernel<<<(NPTS + 255) / 256, 256, 0, stream>>>(sidx, offs, cursor, perm, segp);
  if (useH) {
    gmax_kernel<true><<<(NPTS + RSEG - 1) / RSEG, 512, 0, stream>>>(x, perm, segp, W12, b12, gmaxEnc, hG);
    gpart_kernel<<<NSEG / 8, 256, 0, stream>>>(gmaxEnc, W3gT, b3, gpartG);
    main_v2<<<NPTS / MT, 512, 0, stream>>>(segp, hG, W3hP, W4P, gpartG, b4, out_enc);
  } else {
    gmax_kernel<false><<<(NPTS + RSEG - 1) / RSEG, 512, 0, stream>>>(x, perm, segp, W12, b12, gmaxEnc, hG);
    gpart_kernel<<<NSEG / 8, 256, 0, stream>>>(gmaxEnc, W3gT, b3, gpartG);
    main_kernel<<<NPTS / MT, 512, 0, stream>>>(x, perm, segp, W12, b12,
                                               W3hP, W4P, gpartG, b4, out_enc);
  }
  finalize_kernel<<<(NSEG * EE + 255) / 256, 256, 0, stream>>>(out_enc, out);
}